// Round 15
// baseline (398.759 us; speedup 1.0000x reference)
//
#include <hip/hip_runtime.h>
#include <math.h>

#define M1 100000
#define FF 256
#define UU 256
#define FED 128
#define TT 3
#define EE 131072
#define EPB 32     // edges per tile (k2)
#define TPT 2      // tiles per k2 block (fine-grained: 6144 blocks = 24/CU)
#define EPA 32     // edges per block in fallback atomic kernel
#define SCAN_B 98  // ceil(100000/1024)

typedef __attribute__((ext_vector_type(8))) short short8;
typedef __attribute__((ext_vector_type(4))) short short4v;
typedef __attribute__((ext_vector_type(4))) float f32x4;

// HW bf16 convert (RTNE)
static __device__ __forceinline__ ushort f2bf(float x) {
    union { __bf16 b; ushort u; } c; c.b = (__bf16)x; return c.u;
}
static __device__ __forceinline__ float bf2f(ushort h) {
    union { uint u; float f; } c; c.u = ((uint)h) << 16;
    return c.f;
}

// ---- prep: convert + transpose weights to bf16 [n][k] layouts in ws ----
__global__ __launch_bounds__(256) void k_prep(const float* __restrict__ Wg,
                                              const float* __restrict__ Wge,
                                              const float* __restrict__ Wde,
                                              short* __restrict__ WtG,
                                              short* __restrict__ WtGe,
                                              short* __restrict__ WtDe) {
    const int idx = blockIdx.x * 256 + threadIdx.x;  // 262144 total
    if (idx < 65536) {                               // W_gate: [256k][256n] -> [256n][256k]
        const int n = idx >> 8, k = idx & 255;
        WtG[n * 256 + k] = (short)f2bf(Wg[k * 256 + n]);
    } else {
        int j = idx - 65536;                         // 2*98304 for Wge/Wde
        const float* src = Wge;
        short* dst = WtGe;
        if (j >= 98304) { j -= 98304; src = Wde; dst = WtDe; }
        const int t = j >> 15, rem = j & 32767;      // 32768 per type
        const int n = rem >> 7, k = rem & 127;
        dst[t * 32768 + n * 128 + k] = (short)f2bf(src[t * 32768 + k * 256 + n]);
    }
}

// ---- Kernel 1: src_gated = features @ W_gate, weight-stationary ----
// Single tile per block (3125 blocks = 12/CU -> fine-grained balance).
__global__ __launch_bounds__(1024, 4) void k1_srcgate(const float* __restrict__ feats,
                                                      const short* __restrict__ WtG,
                                                      ushort* __restrict__ sg) {
    __shared__ char As[32 * 512];  // 32 rows x 256 bf16, XOR-swizzled
    const int tid = threadIdx.x, lane = tid & 63, wid = tid >> 6;
    const int r0 = blockIdx.x * 32;

    const int col = wid * 16 + (lane & 15);
    const int ksl = (lane >> 4) * 8;

    // stage 8 floats/thread (coalesced) while weights load
    const int erow = tid >> 5, ekc = tid & 31;
    const float* src = feats + ((size_t)r0 + erow) * FF + ekc * 8;
    const float4 pf0 = *(const float4*)(src);
    const float4 pf1 = *(const float4*)(src + 4);

    short8 wb[8];
#pragma unroll
    for (int ks = 0; ks < 8; ++ks)
        wb[ks] = *(const short8*)(WtG + col * 256 + ks * 32 + ksl);

    {
        short8 v;
        v[0]=(short)f2bf(pf0.x); v[1]=(short)f2bf(pf0.y); v[2]=(short)f2bf(pf0.z); v[3]=(short)f2bf(pf0.w);
        v[4]=(short)f2bf(pf1.x); v[5]=(short)f2bf(pf1.y); v[6]=(short)f2bf(pf1.z); v[7]=(short)f2bf(pf1.w);
        int byte = erow * 512 + ekc * 16;
        byte ^= (erow & 7) << 4;
        *(short8*)(As + byte) = v;
    }
    __syncthreads();

    f32x4 acc[2];
#pragma unroll
    for (int m = 0; m < 2; ++m) acc[m] = (f32x4){0.f, 0.f, 0.f, 0.f};
#pragma unroll
    for (int ks = 0; ks < 8; ++ks) {
#pragma unroll
        for (int m = 0; m < 2; ++m) {
            const int row = m * 16 + (lane & 15);
            int byte = row * 512 + ks * 64 + (lane >> 4) * 16;
            byte ^= (row & 7) << 4;
            const short8 a = *(const short8*)(As + byte);
            acc[m] = __builtin_amdgcn_mfma_f32_16x16x32_bf16(a, wb[ks], acc[m], 0, 0, 0);
        }
    }

#pragma unroll
    for (int m = 0; m < 2; ++m) {
#pragma unroll
        for (int r = 0; r < 4; ++r) {
            const int row = m * 16 + (lane >> 4) * 4 + r;
            sg[(size_t)(r0 + row) * UU + col] = f2bf(acc[m][r]);
        }
    }
}

// ---- sort pipeline: counting sort of edges by destination node, per type ----
__global__ __launch_bounds__(256) void k_hist(const int* __restrict__ eidx,
                                              int* __restrict__ cnt) {
    const int idx = blockIdx.x * 256 + threadIdx.x;   // 393216
    atomicAdd(&cnt[(idx >> 17) * M1 + eidx[idx]], 1);
}

__global__ __launch_bounds__(1024) void k_scan1(int* __restrict__ cnt,
                                                int* __restrict__ part) {
    const int t = blockIdx.x / SCAN_B, b = blockIdx.x % SCAN_B;
    const int i = b * 1024 + threadIdx.x;
    __shared__ int s[1024];
    const int v = (i < M1) ? cnt[t * M1 + i] : 0;
    s[threadIdx.x] = v;
    __syncthreads();
    for (int off = 1; off < 1024; off <<= 1) {
        const int x = (threadIdx.x >= off) ? s[threadIdx.x - off] : 0;
        __syncthreads();
        s[threadIdx.x] += x;
        __syncthreads();
    }
    if (i < M1) cnt[t * M1 + i] = s[threadIdx.x] - v;   // exclusive
    if (threadIdx.x == 1023) part[blockIdx.x] = s[1023];
}

// parallel 98-element exclusive scan per type (3 blocks x 128 threads)
__global__ __launch_bounds__(128) void k_scan2(int* __restrict__ part) {
    const int t = blockIdx.x;
    __shared__ int s[128];
    const int v = (threadIdx.x < SCAN_B) ? part[t * SCAN_B + threadIdx.x] : 0;
    s[threadIdx.x] = v;
    __syncthreads();
    for (int off = 1; off < 128; off <<= 1) {
        const int x = (threadIdx.x >= off) ? s[threadIdx.x - off] : 0;
        __syncthreads();
        s[threadIdx.x] += x;
        __syncthreads();
    }
    if (threadIdx.x < SCAN_B) part[t * SCAN_B + threadIdx.x] = s[threadIdx.x] - v;
}

__global__ __launch_bounds__(1024) void k_scan3(int* __restrict__ cnt,
                                                const int* __restrict__ part) {
    const int t = blockIdx.x / SCAN_B, b = blockIdx.x % SCAN_B;
    const int i = b * 1024 + threadIdx.x;
    if (i < M1) cnt[t * M1 + i] += part[blockIdx.x];
}

__global__ __launch_bounds__(256) void k_scatter(const int* __restrict__ eidx,
                                                 int* __restrict__ cur,
                                                 int* __restrict__ sorted,
                                                 int* __restrict__ snode) {
    const int idx = blockIdx.x * 256 + threadIdx.x;   // 393216
    const int t = idx >> 17;
    const int v = eidx[idx];
    const int slot = atomicAdd(&cur[t * M1 + v], 1);
    sorted[t * EE + slot] = idx & (EE - 1);
    snode[t * EE + slot]  = v;
}
// NOTE: after k_scatter, cnt[t*M1+v] == end offset of node v's segment;
// start(v) = (v==0) ? 0 : cnt[t*M1+v-1].

// ---- Phase A: weight-stationary edge GEMMs, sorted order, CSR msgs ----
// TPT=2 -> 6144 blocks (24/CU): fine-grained load balance. sg values to
// registers (issued post-barrier, consumed after K-loop). Double-buffered
// efeat LDS, one barrier per tile.
__global__ __launch_bounds__(1024, 4) void k2_msgs(const float* __restrict__ efeat,
                                                   const short* __restrict__ WtGe,
                                                   const short* __restrict__ WtDe,
                                                   const float* __restrict__ bd,
                                                   const ushort* __restrict__ sg,
                                                   const int* __restrict__ sorted,
                                                   const int* __restrict__ snode,
                                                   ushort* __restrict__ msgs) {
    __shared__ char As[2][EPB * 256];     // 32 edges x 128 bf16, XOR-swizzled
    const int tid = threadIdx.x, lane = tid & 63, wid = tid >> 6;   // wid 0..15
    const int t = blockIdx.y;
    const int tile0 = blockIdx.x * TPT;

    // wave-resident weights: 16 cols per wave
    const int col = wid * 16 + (lane & 15);
    const int ksl = (lane >> 4) * 8;
    const short* Bg = WtGe + t * 32768;   // [256n][128k]
    const short* Bd = WtDe + t * 32768;
    short8 wg[4], wv[4];
#pragma unroll
    for (int ks = 0; ks < 4; ++ks) {
        wg[ks] = *(const short8*)(Bg + col * 128 + ks * 32 + ksl);
        wv[ks] = *(const short8*)(Bd + col * 128 + ks * 32 + ksl);
    }
    const float bias = bd[t * UU + col];

    const int erow = tid >> 5, ekc = tid & 31;
    const int rbase = (lane >> 4) * 4;    // epilogue row group

    // prefetch efeat tile 0
    float4 pf_e;
    {
        const int base = t * EE + tile0 * EPB;
        const int se = sorted[base + erow];
        pf_e = *(const float4*)(efeat + ((size_t)t * EE + se) * FED + ekc * 4);
    }

#pragma unroll
    for (int it = 0; it < TPT; ++it) {
        const int p = it & 1;
        const int e0 = (tile0 + it) * EPB;
        const int base = t * EE + e0;

        // write staged efeat into buffer p
        {
            short4v v;
            v[0] = (short)f2bf(pf_e.x); v[1] = (short)f2bf(pf_e.y);
            v[2] = (short)f2bf(pf_e.z); v[3] = (short)f2bf(pf_e.w);
            int byte = erow * 256 + ekc * 8;
            byte ^= (erow & 7) << 4;
            *(short4v*)(As[p] + byte) = v;
        }
        __syncthreads();   // buffer p ready

        // issue sg loads for THIS tile (consumed after K-loop) and the
        // efeat prefetch for the NEXT tile — both hide under MFMA.
        ushort sgv[8];
#pragma unroll
        for (int j = 0; j < 8; ++j) {
            const int row = (j >> 2) * 16 + rbase + (j & 3);
            const int nd = snode[base + row];
            sgv[j] = sg[(size_t)nd * UU + col];
        }
        if (it + 1 < TPT) {
            const int nbase = t * EE + (tile0 + it + 1) * EPB;
            const int se = sorted[nbase + erow];
            pf_e = *(const float4*)(efeat + ((size_t)t * EE + se) * FED + ekc * 4);
        }

        // K-loop: pure LDS + MFMA (weights in registers)
        f32x4 accg[2], accv[2];
#pragma unroll
        for (int m = 0; m < 2; ++m) {
            accg[m] = (f32x4){0.f, 0.f, 0.f, 0.f};
            accv[m] = (f32x4){bias, bias, bias, bias};
        }
#pragma unroll
        for (int ks = 0; ks < 4; ++ks) {
#pragma unroll
            for (int m = 0; m < 2; ++m) {
                const int row = m * 16 + (lane & 15);
                int byte = row * 256 + ks * 64 + (lane >> 4) * 16;
                byte ^= (row & 7) << 4;
                const short8 a = *(const short8*)(As[p] + byte);
                accg[m] = __builtin_amdgcn_mfma_f32_16x16x32_bf16(a, wg[ks], accg[m], 0, 0, 0);
                accv[m] = __builtin_amdgcn_mfma_f32_16x16x32_bf16(a, wv[ks], accv[m], 0, 0, 0);
            }
        }

        // epilogue: sigmoid gate (sg from registers), store at sorted pos
#pragma unroll
        for (int m = 0; m < 2; ++m) {
#pragma unroll
            for (int r = 0; r < 4; ++r) {
                const float sgf = bf2f(sgv[m * 4 + r]);
                const float e = __expf(-(sgf + accg[m][r]));
                const float g = __builtin_amdgcn_rcpf(1.f + e);
                const float msg = accv[m][r] * g;
                const int row = m * 16 + rbase + r;
                msgs[((size_t)t * EE + e0 + row) * UU + col] = f2bf(msg);
            }
        }
        // next iteration writes buffer p^1 (no trailing barrier needed)
    }
}

// ---- Phase B: per-node contiguous segment reduce, 2-way unrolled ----
__global__ __launch_bounds__(256, 8) void k3_reduce(const int* __restrict__ cnt,
                                                    const ushort* __restrict__ msgs,
                                                    float* __restrict__ out) {
    const int tid = threadIdx.x, lane = tid & 63, w = tid >> 6;
    const int v = blockIdx.x * 4 + w;   // node id, 4 waves/block; grid=25000
    float a0 = 0.f, a1 = 0.f, a2 = 0.f, a3 = 0.f;
#pragma unroll
    for (int t = 0; t < TT; ++t) {
        const int end   = cnt[t * M1 + v];
        const int start = (v == 0) ? 0 : cnt[t * M1 + v - 1];
        const ushort* base = msgs + (size_t)t * EE * UU + lane * 4;
        int e = start;
        for (; e + 1 < end; e += 2) {                 // 2 loads in flight
            const uint2 d0 = *(const uint2*)(base + (size_t)e * UU);
            const uint2 d1 = *(const uint2*)(base + (size_t)(e + 1) * UU);
            a0 += bf2f((ushort)(d0.x & 0xffff)) + bf2f((ushort)(d1.x & 0xffff));
            a1 += bf2f((ushort)(d0.x >> 16))    + bf2f((ushort)(d1.x >> 16));
            a2 += bf2f((ushort)(d0.y & 0xffff)) + bf2f((ushort)(d1.y & 0xffff));
            a3 += bf2f((ushort)(d0.y >> 16))    + bf2f((ushort)(d1.y >> 16));
        }
        if (e < end) {
            const uint2 d0 = *(const uint2*)(base + (size_t)e * UU);
            a0 += bf2f((ushort)(d0.x & 0xffff));
            a1 += bf2f((ushort)(d0.x >> 16));
            a2 += bf2f((ushort)(d0.y & 0xffff));
            a3 += bf2f((ushort)(d0.y >> 16));
        }
    }
    float4 o; o.x = a0; o.y = a1; o.z = a2; o.w = a3;
    *(float4*)(out + (size_t)v * UU + lane * 4) = o;
}

// ---- Fallback (small ws): sorted + atomic kernel (EPA=32) ----
__global__ __launch_bounds__(256, 4) void k2_edges(const int* __restrict__ eidx,
                                                   const float* __restrict__ efeat,
                                                   const short* __restrict__ WtGe,
                                                   const short* __restrict__ WtDe,
                                                   const float* __restrict__ bd,
                                                   const ushort* __restrict__ sg,
                                                   const int* __restrict__ sorted,
                                                   float* __restrict__ out) {
    __shared__ char As[EPA * 256];
    __shared__ ushort sgl[EPA][260];
    __shared__ int nds[EPA];
    const int tid = threadIdx.x, lane = tid & 63, wid = tid >> 6;
    const int t = blockIdx.y;
    const int e0 = blockIdx.x * EPA;
    const int* sortedT = sorted + t * EE + e0;
    const int* eidxT   = eidx + t * EE;

    if (tid < EPA) nds[tid] = eidxT[sortedT[tid]];
#pragma unroll
    for (int j = 0; j < 2; ++j) {
        const int chunk = j * 256 + tid;
        const int row = chunk >> 4, kc = chunk & 15;
        const int se = sortedT[row];
        const float* src = efeat + ((size_t)t * EE + se) * FED + kc * 8;
        const float4 f0 = *(const float4*)(src);
        const float4 f1 = *(const float4*)(src + 4);
        short8 v;
        v[0]=(short)f2bf(f0.x); v[1]=(short)f2bf(f0.y); v[2]=(short)f2bf(f0.z); v[3]=(short)f2bf(f0.w);
        v[4]=(short)f2bf(f1.x); v[5]=(short)f2bf(f1.y); v[6]=(short)f2bf(f1.z); v[7]=(short)f2bf(f1.w);
        int byte = row * 256 + kc * 16;
        byte ^= (row & 7) << 4;
        *(short8*)(As + byte) = v;
    }
    __syncthreads();
#pragma unroll
    for (int j = 0; j < 16; ++j) {
        const int item = j * 256 + tid;
        const int row = item >> 7, c2 = item & 127;
        const uint v = *(const uint*)(sg + (size_t)nds[row] * UU + c2 * 2);
        *(uint*)&sgl[row][c2 * 2] = v;
    }
    const short* Bg = WtGe + t * 32768;
    const short* Bd = WtDe + t * 32768;
    const int nb = wid * 64;
    f32x4 accg[2][4], accv[2][4];
#pragma unroll
    for (int m = 0; m < 2; ++m)
#pragma unroll
        for (int n = 0; n < 4; ++n) {
            accg[m][n] = (f32x4){0.f, 0.f, 0.f, 0.f};
            accv[m][n] = (f32x4){0.f, 0.f, 0.f, 0.f};
        }
#pragma unroll
    for (int ks = 0; ks < 4; ++ks) {
        short8 a[2];
#pragma unroll
        for (int m = 0; m < 2; ++m) {
            const int row = m * 16 + (lane & 15);
            int byte = row * 256 + ks * 64 + (lane >> 4) * 16;
            byte ^= (row & 7) << 4;
            a[m] = *(const short8*)(As + byte);
        }
#pragma unroll
        for (int n = 0; n < 4; ++n) {
            const int col = nb + n * 16 + (lane & 15);
            const int koff = ks * 32 + (lane >> 4) * 8;
            const short8 bg = *(const short8*)(Bg + col * 128 + koff);
            const short8 bv = *(const short8*)(Bd + col * 128 + koff);
#pragma unroll
            for (int m = 0; m < 2; ++m) {
                accg[m][n] = __builtin_amdgcn_mfma_f32_16x16x32_bf16(a[m], bg, accg[m][n], 0, 0, 0);
                accv[m][n] = __builtin_amdgcn_mfma_f32_16x16x32_bf16(a[m], bv, accv[m][n], 0, 0, 0);
            }
        }
    }
    __syncthreads();
    float bias[4];
#pragma unroll
    for (int n = 0; n < 4; ++n) bias[n] = bd[t * UU + nb + n * 16 + (lane & 15)];
#pragma unroll
    for (int m = 0; m < 2; ++m) {
        const int ebase = m * 16 + (lane >> 4) * 4;
        int node[4];
#pragma unroll
        for (int r = 0; r < 4; ++r) node[r] = nds[ebase + r];
#pragma unroll
        for (int n = 0; n < 4; ++n) {
            const int col = nb + n * 16 + (lane & 15);
            float carry = 0.f;
#pragma unroll
            for (int r = 0; r < 4; ++r) {
                const float sgv = bf2f(sgl[ebase + r][col]);
                const float e = __expf(-(sgv + accg[m][n][r]));
                const float g = __builtin_amdgcn_rcpf(1.f + e);
                carry += (accv[m][n][r] + bias[n]) * g;
                if (r == 3 || node[r + 1] != node[r]) {
                    atomicAdd(&out[(size_t)node[r] * UU + col], carry);
                    carry = 0.f;
                }
            }
        }
    }
}

extern "C" void kernel_launch(void* const* d_in, const int* in_sizes, int n_in,
                              void* d_out, int out_size, void* d_ws, size_t ws_size,
                              hipStream_t stream) {
    const float* feats = (const float*)d_in[0];
    const int*   eidx  = (const int*)d_in[1];
    const float* efeat = (const float*)d_in[2];
    const float* Wg    = (const float*)d_in[3];
    const float* Wge   = (const float*)d_in[4];
    const float* Wde   = (const float*)d_in[5];
    const float* bd    = (const float*)d_in[6];
    float* out = (float*)d_out;

    char* ws = (char*)d_ws;
    size_t off = 0;
    auto alloc = [&](size_t bytes) { char* p = ws + off; off = (off + bytes + 511) & ~(size_t)511; return p; };
    ushort* sg   = (ushort*)alloc((size_t)M1 * UU * 2);          // 51.2 MB
    short* WtG   = (short*)alloc(256 * 256 * 2);
    short* WtGe  = (short*)alloc((size_t)TT * FED * UU * 2);
    short* WtDe  = (short*)alloc((size_t)TT * FED * UU * 2);
    int* cnt     = (int*)alloc((size_t)TT * M1 * 4);             // 1.2 MB
    int* part    = (int*)alloc(4096);
    int* sorted  = (int*)alloc((size_t)TT * EE * 4);             // 1.57 MB
    int* snode   = (int*)alloc((size_t)TT * EE * 4);             // 1.57 MB
    const size_t small_needed = off;
    ushort* msgs = (ushort*)alloc((size_t)TT * EE * UU * 2);     // 201.3 MB
    const size_t big_needed = off;

    hipMemsetAsync(cnt, 0, (size_t)TT * M1 * 4, stream);
    k_prep<<<262144 / 256, 256, 0, stream>>>(Wg, Wge, Wde, WtG, WtGe, WtDe);
    k1_srcgate<<<M1 / 32, 1024, 0, stream>>>(feats, WtG, sg);

    k_hist<<<(TT * EE) / 256, 256, 0, stream>>>(eidx, cnt);
    k_scan1<<<TT * SCAN_B, 1024, 0, stream>>>(cnt, part);
    k_scan2<<<TT, 128, 0, stream>>>(part);
    k_scan3<<<TT * SCAN_B, 1024, 0, stream>>>(cnt, part);
    k_scatter<<<(TT * EE) / 256, 256, 0, stream>>>(eidx, cnt, sorted, snode);

    if (ws_size >= big_needed) {
        k2_msgs<<<dim3((EE / EPB) / TPT, TT), 1024, 0, stream>>>(efeat, WtGe, WtDe, bd,
                                                                 (const ushort*)sg, sorted, snode, msgs);
        k3_reduce<<<M1 / 4, 256, 0, stream>>>(cnt, (const ushort*)msgs, out);
    } else if (ws_size >= small_needed) {
        hipMemsetAsync(d_out, 0, (size_t)out_size * sizeof(float), stream);
        k2_edges<<<dim3(EE / EPA, TT), 256, 0, stream>>>(eidx, efeat, WtGe, WtDe, bd,
                                                         (const ushort*)sg, sorted, out);
    }
}

// Round 16
// 333.721 us; speedup vs baseline: 1.1949x; 1.1949x over previous
//
#include <hip/hip_runtime.h>
#include <math.h>

#define M1 100000
#define FF 256
#define UU 256
#define FED 128
#define TT 3
#define EE 131072
#define EPB 32     // edges per tile (k2)
#define TPT 8      // tiles per k2 block
#define TPT1 5     // tiles per k1 block (3125 = 625*5)
#define EPA 32     // edges per block in fallback atomic kernel
#define SCAN_B 98  // ceil(100000/1024)

typedef __attribute__((ext_vector_type(8))) short short8;
typedef __attribute__((ext_vector_type(4))) short short4v;
typedef __attribute__((ext_vector_type(4))) float f32x4;

// HW bf16 convert (RTNE)
static __device__ __forceinline__ ushort f2bf(float x) {
    union { __bf16 b; ushort u; } c; c.b = (__bf16)x; return c.u;
}
static __device__ __forceinline__ float bf2f(ushort h) {
    union { uint u; float f; } c; c.u = ((uint)h) << 16;
    return c.f;
}

// ---- prep: convert + transpose weights to bf16 [n][k] layouts in ws ----
__global__ __launch_bounds__(256) void k_prep(const float* __restrict__ Wg,
                                              const float* __restrict__ Wge,
                                              const float* __restrict__ Wde,
                                              short* __restrict__ WtG,
                                              short* __restrict__ WtGe,
                                              short* __restrict__ WtDe) {
    const int idx = blockIdx.x * 256 + threadIdx.x;  // 262144 total
    if (idx < 65536) {                               // W_gate: [256k][256n] -> [256n][256k]
        const int n = idx >> 8, k = idx & 255;
        WtG[n * 256 + k] = (short)f2bf(Wg[k * 256 + n]);
    } else {
        int j = idx - 65536;                         // 2*98304 for Wge/Wde
        const float* src = Wge;
        short* dst = WtGe;
        if (j >= 98304) { j -= 98304; src = Wde; dst = WtDe; }
        const int t = j >> 15, rem = j & 32767;      // 32768 per type
        const int n = rem >> 7, k = rem & 127;
        dst[t * 32768 + n * 128 + k] = (short)f2bf(src[t * 32768 + k * 256 + n]);
    }
}

// ---- Kernel 1: src_gated = features @ W_gate, weight-stationary ----
// (round-12 config: TPT1=5, double-buffered LDS, 1 barrier/tile)
__global__ __launch_bounds__(1024, 4) void k1_srcgate(const float* __restrict__ feats,
                                                      const short* __restrict__ WtG,
                                                      ushort* __restrict__ sg) {
    __shared__ char As[2][32 * 512];  // 32 rows x 256 bf16, XOR-swizzled
    const int tid = threadIdx.x, lane = tid & 63, wid = tid >> 6;
    const int tile0 = blockIdx.x * TPT1;

    const int col = wid * 16 + (lane & 15);
    const int ksl = (lane >> 4) * 8;
    short8 wb[8];
#pragma unroll
    for (int ks = 0; ks < 8; ++ks)
        wb[ks] = *(const short8*)(WtG + col * 256 + ks * 32 + ksl);

    const int erow = tid >> 5, ekc = tid & 31;   // stage 8 floats/thread
    float4 pf0, pf1;
    {
        const float* src = feats + ((size_t)(tile0 * 32) + erow) * FF + ekc * 8;
        pf0 = *(const float4*)(src);
        pf1 = *(const float4*)(src + 4);
    }

    for (int it = 0; it < TPT1; ++it) {
        const int p = it & 1;
        {
            short8 v;
            v[0]=(short)f2bf(pf0.x); v[1]=(short)f2bf(pf0.y); v[2]=(short)f2bf(pf0.z); v[3]=(short)f2bf(pf0.w);
            v[4]=(short)f2bf(pf1.x); v[5]=(short)f2bf(pf1.y); v[6]=(short)f2bf(pf1.z); v[7]=(short)f2bf(pf1.w);
            int byte = erow * 512 + ekc * 16;
            byte ^= (erow & 7) << 4;
            *(short8*)(As[p] + byte) = v;
        }
        __syncthreads();

        if (it + 1 < TPT1) {
            const float* src = feats + ((size_t)((tile0 + it + 1) * 32) + erow) * FF + ekc * 8;
            pf0 = *(const float4*)(src);
            pf1 = *(const float4*)(src + 4);
        }

        f32x4 acc[2];
#pragma unroll
        for (int m = 0; m < 2; ++m) acc[m] = (f32x4){0.f, 0.f, 0.f, 0.f};
#pragma unroll
        for (int ks = 0; ks < 8; ++ks) {
#pragma unroll
            for (int m = 0; m < 2; ++m) {
                const int row = m * 16 + (lane & 15);
                int byte = row * 512 + ks * 64 + (lane >> 4) * 16;
                byte ^= (row & 7) << 4;
                const short8 a = *(const short8*)(As[p] + byte);
                acc[m] = __builtin_amdgcn_mfma_f32_16x16x32_bf16(a, wb[ks], acc[m], 0, 0, 0);
            }
        }

        const int r0 = (tile0 + it) * 32;
#pragma unroll
        for (int m = 0; m < 2; ++m) {
#pragma unroll
            for (int r = 0; r < 4; ++r) {
                const int row = m * 16 + (lane >> 4) * 4 + r;
                sg[(size_t)(r0 + row) * UU + col] = f2bf(acc[m][r]);
            }
        }
    }
}

// ---- sort pipeline: counting sort of edges by destination node, per type ----
__global__ __launch_bounds__(256) void k_hist(const int* __restrict__ eidx,
                                              int* __restrict__ cnt) {
    const int idx = blockIdx.x * 256 + threadIdx.x;   // 393216
    atomicAdd(&cnt[(idx >> 17) * M1 + eidx[idx]], 1);
}

__global__ __launch_bounds__(1024) void k_scan1(int* __restrict__ cnt,
                                                int* __restrict__ part) {
    const int t = blockIdx.x / SCAN_B, b = blockIdx.x % SCAN_B;
    const int i = b * 1024 + threadIdx.x;
    __shared__ int s[1024];
    const int v = (i < M1) ? cnt[t * M1 + i] : 0;
    s[threadIdx.x] = v;
    __syncthreads();
    for (int off = 1; off < 1024; off <<= 1) {
        const int x = (threadIdx.x >= off) ? s[threadIdx.x - off] : 0;
        __syncthreads();
        s[threadIdx.x] += x;
        __syncthreads();
    }
    if (i < M1) cnt[t * M1 + i] = s[threadIdx.x] - v;   // exclusive
    if (threadIdx.x == 1023) part[blockIdx.x] = s[1023];
}

// parallel 98-element exclusive scan per type (3 blocks x 128 threads)
__global__ __launch_bounds__(128) void k_scan2(int* __restrict__ part) {
    const int t = blockIdx.x;
    __shared__ int s[128];
    const int v = (threadIdx.x < SCAN_B) ? part[t * SCAN_B + threadIdx.x] : 0;
    s[threadIdx.x] = v;
    __syncthreads();
    for (int off = 1; off < 128; off <<= 1) {
        const int x = (threadIdx.x >= off) ? s[threadIdx.x - off] : 0;
        __syncthreads();
        s[threadIdx.x] += x;
        __syncthreads();
    }
    if (threadIdx.x < SCAN_B) part[t * SCAN_B + threadIdx.x] = s[threadIdx.x] - v;
}

__global__ __launch_bounds__(1024) void k_scan3(int* __restrict__ cnt,
                                                const int* __restrict__ part) {
    const int t = blockIdx.x / SCAN_B, b = blockIdx.x % SCAN_B;
    const int i = b * 1024 + threadIdx.x;
    if (i < M1) cnt[t * M1 + i] += part[blockIdx.x];
}

// scatter: also emit rank[] (edge -> sorted slot, the inverse permutation)
__global__ __launch_bounds__(256) void k_scatter(const int* __restrict__ eidx,
                                                 int* __restrict__ cur,
                                                 int* __restrict__ sorted,
                                                 int* __restrict__ rank) {
    const int idx = blockIdx.x * 256 + threadIdx.x;   // 393216
    const int t = idx >> 17;
    const int v = eidx[idx];
    const int slot = atomicAdd(&cur[t * M1 + v], 1);
    sorted[t * EE + slot] = idx & (EE - 1);
    rank[idx] = slot;
}
// NOTE: after k_scatter, cnt[t*M1+v] == end offset of node v's segment;
// start(v) = (v==0) ? 0 : cnt[t*M1+v-1].

// ---- Phase A: weight-stationary edge GEMMs, LINEAR order, scatter-write ----
// Reads are fully coalesced (efeat linear, eidx linear); the random part is
// moved to the msgs WRITE (fire-and-forget 512B rows at rank[] slots) so no
// wave ever stalls on a gathered read except the small sg 2B gather.
__global__ __launch_bounds__(1024, 4) void k2_msgs(const float* __restrict__ efeat,
                                                   const short* __restrict__ WtGe,
                                                   const short* __restrict__ WtDe,
                                                   const float* __restrict__ bd,
                                                   const ushort* __restrict__ sg,
                                                   const int* __restrict__ eidx,
                                                   const int* __restrict__ rank,
                                                   ushort* __restrict__ msgs) {
    __shared__ char As[2][EPB * 256];     // 32 edges x 128 bf16, XOR-swizzled
    const int tid = threadIdx.x, lane = tid & 63, wid = tid >> 6;   // wid 0..15
    const int t = blockIdx.y;
    const int tile0 = blockIdx.x * TPT;

    // wave-resident weights: 16 cols per wave
    const int col = wid * 16 + (lane & 15);
    const int ksl = (lane >> 4) * 8;
    const short* Bg = WtGe + t * 32768;   // [256n][128k]
    const short* Bd = WtDe + t * 32768;
    short8 wg[4], wv[4];
#pragma unroll
    for (int ks = 0; ks < 4; ++ks) {
        wg[ks] = *(const short8*)(Bg + col * 128 + ks * 32 + ksl);
        wv[ks] = *(const short8*)(Bd + col * 128 + ks * 32 + ksl);
    }
    const float bias = bd[t * UU + col];

    const int erow = tid >> 5, ekc = tid & 31;
    const int rbase = (lane >> 4) * 4;    // epilogue row group

    // prefetch efeat tile 0 (LINEAR, coalesced)
    float4 pf_e;
    {
        const int e0 = tile0 * EPB;
        pf_e = *(const float4*)(efeat + ((size_t)t * EE + e0 + erow) * FED + ekc * 4);
    }

    for (int it = 0; it < TPT; ++it) {
        const int p = it & 1;
        const int e0 = (tile0 + it) * EPB;
        const int base = t * EE + e0;

        // write staged efeat into buffer p
        {
            short4v v;
            v[0] = (short)f2bf(pf_e.x); v[1] = (short)f2bf(pf_e.y);
            v[2] = (short)f2bf(pf_e.z); v[3] = (short)f2bf(pf_e.w);
            int byte = erow * 256 + ekc * 8;
            byte ^= (erow & 7) << 4;
            *(short4v*)(As[p] + byte) = v;
        }
        __syncthreads();   // buffer p ready

        // issue sg gather (via eidx direct) + rank loads + next-tile prefetch;
        // all consumed after the K-loop -> latency hides under MFMA.
        ushort sgv[8];
        int slot[8];
#pragma unroll
        for (int j = 0; j < 8; ++j) {
            const int row = (j >> 2) * 16 + rbase + (j & 3);
            const int nd = eidx[base + row];          // L1-broadcast
            sgv[j] = sg[(size_t)nd * UU + col];       // random 2B gather
            slot[j] = rank[base + row];               // L1-broadcast
        }
        if (it + 1 < TPT) {
            const int ne0 = (tile0 + it + 1) * EPB;
            pf_e = *(const float4*)(efeat + ((size_t)t * EE + ne0 + erow) * FED + ekc * 4);
        }

        // K-loop: pure LDS + MFMA (weights in registers)
        f32x4 accg[2], accv[2];
#pragma unroll
        for (int m = 0; m < 2; ++m) {
            accg[m] = (f32x4){0.f, 0.f, 0.f, 0.f};
            accv[m] = (f32x4){bias, bias, bias, bias};
        }
#pragma unroll
        for (int ks = 0; ks < 4; ++ks) {
#pragma unroll
            for (int m = 0; m < 2; ++m) {
                const int row = m * 16 + (lane & 15);
                int byte = row * 256 + ks * 64 + (lane >> 4) * 16;
                byte ^= (row & 7) << 4;
                const short8 a = *(const short8*)(As[p] + byte);
                accg[m] = __builtin_amdgcn_mfma_f32_16x16x32_bf16(a, wg[ks], accg[m], 0, 0, 0);
                accv[m] = __builtin_amdgcn_mfma_f32_16x16x32_bf16(a, wv[ks], accv[m], 0, 0, 0);
            }
        }

        // epilogue: sigmoid gate, SCATTER-write msg row to its sorted slot
#pragma unroll
        for (int m = 0; m < 2; ++m) {
#pragma unroll
            for (int r = 0; r < 4; ++r) {
                const int j = m * 4 + r;
                const float sgf = bf2f(sgv[j]);
                const float e = __expf(-(sgf + accg[m][r]));
                const float g = __builtin_amdgcn_rcpf(1.f + e);
                const float msg = accv[m][r] * g;
                msgs[((size_t)t * EE + slot[j]) * UU + col] = f2bf(msg);
            }
        }
        // next iteration writes buffer p^1 (no trailing barrier needed)
    }
}

// ---- Phase B: per-node contiguous segment reduce, 2-way unrolled ----
__global__ __launch_bounds__(256, 8) void k3_reduce(const int* __restrict__ cnt,
                                                    const ushort* __restrict__ msgs,
                                                    float* __restrict__ out) {
    const int tid = threadIdx.x, lane = tid & 63, w = tid >> 6;
    const int v = blockIdx.x * 4 + w;   // node id, 4 waves/block; grid=25000
    float a0 = 0.f, a1 = 0.f, a2 = 0.f, a3 = 0.f;
#pragma unroll
    for (int t = 0; t < TT; ++t) {
        const int end   = cnt[t * M1 + v];
        const int start = (v == 0) ? 0 : cnt[t * M1 + v - 1];
        const ushort* base = msgs + (size_t)t * EE * UU + lane * 4;
        int e = start;
        for (; e + 1 < end; e += 2) {                 // 2 loads in flight
            const uint2 d0 = *(const uint2*)(base + (size_t)e * UU);
            const uint2 d1 = *(const uint2*)(base + (size_t)(e + 1) * UU);
            a0 += bf2f((ushort)(d0.x & 0xffff)) + bf2f((ushort)(d1.x & 0xffff));
            a1 += bf2f((ushort)(d0.x >> 16))    + bf2f((ushort)(d1.x >> 16));
            a2 += bf2f((ushort)(d0.y & 0xffff)) + bf2f((ushort)(d1.y & 0xffff));
            a3 += bf2f((ushort)(d0.y >> 16))    + bf2f((ushort)(d1.y >> 16));
        }
        if (e < end) {
            const uint2 d0 = *(const uint2*)(base + (size_t)e * UU);
            a0 += bf2f((ushort)(d0.x & 0xffff));
            a1 += bf2f((ushort)(d0.x >> 16));
            a2 += bf2f((ushort)(d0.y & 0xffff));
            a3 += bf2f((ushort)(d0.y >> 16));
        }
    }
    float4 o; o.x = a0; o.y = a1; o.z = a2; o.w = a3;
    *(float4*)(out + (size_t)v * UU + lane * 4) = o;
}

// ---- Fallback (small ws): sorted + atomic kernel (EPA=32) ----
__global__ __launch_bounds__(256, 4) void k2_edges(const int* __restrict__ eidx,
                                                   const float* __restrict__ efeat,
                                                   const short* __restrict__ WtGe,
                                                   const short* __restrict__ WtDe,
                                                   const float* __restrict__ bd,
                                                   const ushort* __restrict__ sg,
                                                   const int* __restrict__ sorted,
                                                   float* __restrict__ out) {
    __shared__ char As[EPA * 256];
    __shared__ ushort sgl[EPA][260];
    __shared__ int nds[EPA];
    const int tid = threadIdx.x, lane = tid & 63, wid = tid >> 6;
    const int t = blockIdx.y;
    const int e0 = blockIdx.x * EPA;
    const int* sortedT = sorted + t * EE + e0;
    const int* eidxT   = eidx + t * EE;

    if (tid < EPA) nds[tid] = eidxT[sortedT[tid]];
#pragma unroll
    for (int j = 0; j < 2; ++j) {
        const int chunk = j * 256 + tid;
        const int row = chunk >> 4, kc = chunk & 15;
        const int se = sortedT[row];
        const float* src = efeat + ((size_t)t * EE + se) * FED + kc * 8;
        const float4 f0 = *(const float4*)(src);
        const float4 f1 = *(const float4*)(src + 4);
        short8 v;
        v[0]=(short)f2bf(f0.x); v[1]=(short)f2bf(f0.y); v[2]=(short)f2bf(f0.z); v[3]=(short)f2bf(f0.w);
        v[4]=(short)f2bf(f1.x); v[5]=(short)f2bf(f1.y); v[6]=(short)f2bf(f1.z); v[7]=(short)f2bf(f1.w);
        int byte = row * 256 + kc * 16;
        byte ^= (row & 7) << 4;
        *(short8*)(As + byte) = v;
    }
    __syncthreads();
#pragma unroll
    for (int j = 0; j < 16; ++j) {
        const int item = j * 256 + tid;
        const int row = item >> 7, c2 = item & 127;
        const uint v = *(const uint*)(sg + (size_t)nds[row] * UU + c2 * 2);
        *(uint*)&sgl[row][c2 * 2] = v;
    }
    const short* Bg = WtGe + t * 32768;
    const short* Bd = WtDe + t * 32768;
    const int nb = wid * 64;
    f32x4 accg[2][4], accv[2][4];
#pragma unroll
    for (int m = 0; m < 2; ++m)
#pragma unroll
        for (int n = 0; n < 4; ++n) {
            accg[m][n] = (f32x4){0.f, 0.f, 0.f, 0.f};
            accv[m][n] = (f32x4){0.f, 0.f, 0.f, 0.f};
        }
#pragma unroll
    for (int ks = 0; ks < 4; ++ks) {
        short8 a[2];
#pragma unroll
        for (int m = 0; m < 2; ++m) {
            const int row = m * 16 + (lane & 15);
            int byte = row * 256 + ks * 64 + (lane >> 4) * 16;
            byte ^= (row & 7) << 4;
            a[m] = *(const short8*)(As + byte);
        }
#pragma unroll
        for (int n = 0; n < 4; ++n) {
            const int col = nb + n * 16 + (lane & 15);
            const int koff = ks * 32 + (lane >> 4) * 8;
            const short8 bg = *(const short8*)(Bg + col * 128 + koff);
            const short8 bv = *(const short8*)(Bd + col * 128 + koff);
#pragma unroll
            for (int m = 0; m < 2; ++m) {
                accg[m][n] = __builtin_amdgcn_mfma_f32_16x16x32_bf16(a[m], bg, accg[m][n], 0, 0, 0);
                accv[m][n] = __builtin_amdgcn_mfma_f32_16x16x32_bf16(a[m], bv, accv[m][n], 0, 0, 0);
            }
        }
    }
    __syncthreads();
    float bias[4];
#pragma unroll
    for (int n = 0; n < 4; ++n) bias[n] = bd[t * UU + nb + n * 16 + (lane & 15)];
#pragma unroll
    for (int m = 0; m < 2; ++m) {
        const int ebase = m * 16 + (lane >> 4) * 4;
        int node[4];
#pragma unroll
        for (int r = 0; r < 4; ++r) node[r] = nds[ebase + r];
#pragma unroll
        for (int n = 0; n < 4; ++n) {
            const int col = nb + n * 16 + (lane & 15);
            float carry = 0.f;
#pragma unroll
            for (int r = 0; r < 4; ++r) {
                const float sgv = bf2f(sgl[ebase + r][col]);
                const float e = __expf(-(sgv + accg[m][n][r]));
                const float g = __builtin_amdgcn_rcpf(1.f + e);
                carry += (accv[m][n][r] + bias[n]) * g;
                if (r == 3 || node[r + 1] != node[r]) {
                    atomicAdd(&out[(size_t)node[r] * UU + col], carry);
                    carry = 0.f;
                }
            }
        }
    }
}

extern "C" void kernel_launch(void* const* d_in, const int* in_sizes, int n_in,
                              void* d_out, int out_size, void* d_ws, size_t ws_size,
                              hipStream_t stream) {
    const float* feats = (const float*)d_in[0];
    const int*   eidx  = (const int*)d_in[1];
    const float* efeat = (const float*)d_in[2];
    const float* Wg    = (const float*)d_in[3];
    const float* Wge   = (const float*)d_in[4];
    const float* Wde   = (const float*)d_in[5];
    const float* bd    = (const float*)d_in[6];
    float* out = (float*)d_out;

    char* ws = (char*)d_ws;
    size_t off = 0;
    auto alloc = [&](size_t bytes) { char* p = ws + off; off = (off + bytes + 511) & ~(size_t)511; return p; };
    ushort* sg   = (ushort*)alloc((size_t)M1 * UU * 2);          // 51.2 MB
    short* WtG   = (short*)alloc(256 * 256 * 2);
    short* WtGe  = (short*)alloc((size_t)TT * FED * UU * 2);
    short* WtDe  = (short*)alloc((size_t)TT * FED * UU * 2);
    int* cnt     = (int*)alloc((size_t)TT * M1 * 4);             // 1.2 MB
    int* part    = (int*)alloc(4096);
    int* sorted  = (int*)alloc((size_t)TT * EE * 4);             // 1.57 MB
    int* rank    = (int*)alloc((size_t)TT * EE * 4);             // 1.57 MB
    const size_t small_needed = off;
    ushort* msgs = (ushort*)alloc((size_t)TT * EE * UU * 2);     // 201.3 MB
    const size_t big_needed = off;

    hipMemsetAsync(cnt, 0, (size_t)TT * M1 * 4, stream);
    k_prep<<<262144 / 256, 256, 0, stream>>>(Wg, Wge, Wde, WtG, WtGe, WtDe);
    k1_srcgate<<<M1 / 32 / TPT1, 1024, 0, stream>>>(feats, WtG, sg);

    k_hist<<<(TT * EE) / 256, 256, 0, stream>>>(eidx, cnt);
    k_scan1<<<TT * SCAN_B, 1024, 0, stream>>>(cnt, part);
    k_scan2<<<TT, 128, 0, stream>>>(part);
    k_scan3<<<TT * SCAN_B, 1024, 0, stream>>>(cnt, part);
    k_scatter<<<(TT * EE) / 256, 256, 0, stream>>>(eidx, cnt, sorted, rank);

    if (ws_size >= big_needed) {
        k2_msgs<<<dim3((EE / EPB) / TPT, TT), 1024, 0, stream>>>(efeat, WtGe, WtDe, bd,
                                                                 (const ushort*)sg, eidx, rank, msgs);
        k3_reduce<<<M1 / 4, 256, 0, stream>>>(cnt, (const ushort*)msgs, out);
    } else if (ws_size >= small_needed) {
        hipMemsetAsync(d_out, 0, (size_t)out_size * sizeof(float), stream);
        k2_edges<<<dim3(EE / EPA, TT), 256, 0, stream>>>(eidx, efeat, WtGe, WtDe, bd,
                                                         (const ushort*)sg, sorted, out);
    }
}